// Round 3
// baseline (1565.436 us; speedup 1.0000x reference)
//
#include <hip/hip_runtime.h>
#include <math.h>

#define NLVL 16
#define TSIZE 16384
#define BLK 1024
#define PPT 2                 // points per thread
#define PPB (BLK * PPT)       // points per block

typedef float floatx4 __attribute__((ext_vector_type(4)));

struct NsArg { float nf[NLVL]; };

__global__ __launch_bounds__(BLK, 4) void hashgrid_lds(
    const float* __restrict__ inp,
    const float2* __restrict__ tbl,
    float* __restrict__ out,
    NsArg ns, int npts)
{
    __shared__ float2 sh[TSIZE];          // 128 KiB: one level's table
    const unsigned P1 = 2654435761u, P2 = 805459861u;
    const int tid = threadIdx.x;
    const int base = blockIdx.x * PPB;

    // Load coordinates for PPT points per thread.
    float X0[PPT], X1[PPT], X2[PPT];
    int nn[PPT];
#pragma unroll
    for (int p = 0; p < PPT; ++p) {
        int n = base + tid + p * BLK;
        nn[p] = n;
        int m = n < npts ? n : 0;
        X0[p] = (inp[3*m+0] + 3.0f) / 6.0f;
        X1[p] = (inp[3*m+1] + 3.0f) / 6.0f;
        X2[p] = (inp[3*m+2] + 3.0f) / 6.0f;
    }

    float res[PPT][2*NLVL];

#pragma unroll
    for (int l = 0; l < NLVL; ++l) {
        // ---- stage level-l table into LDS (coalesced float4) ----
        {
            const floatx4* src = (const floatx4*)(tbl + l * TSIZE);
            floatx4* dst = (floatx4*)sh;
#pragma unroll
            for (int k = 0; k < (TSIZE/2)/BLK; ++k)   // 8 iters
                dst[tid + k*BLK] = src[tid + k*BLK];
        }
        __syncthreads();

        const float Nf = ns.nf[l];
#pragma unroll
        for (int p = 0; p < PPT; ++p) {
            float t0 = X0[p] * Nf, t1 = X1[p] * Nf, t2 = X2[p] * Nf;
            float fl0 = floorf(t0), fl1 = floorf(t1), fl2 = floorf(t2);
            float p0 = t0 - fl0, p1 = t1 - fl1, p2 = t2 - fl2;
            unsigned m0 = (unsigned)fl0, m1 = (unsigned)fl1, m2 = (unsigned)fl2;
            unsigned a0 = m0,      a1 = m0 + 1u;
            unsigned b0 = m1 * P1, b1 = b0 + P1;
            unsigned c0 = m2 * P2, c1 = c0 + P2;
            float q0 = 1.0f - p0, q1 = 1.0f - p1, q2 = 1.0f - p2;
            float w00 = q0*q1, w01 = q0*p1, w10 = p0*q1, w11 = p0*p1;
            float acc0 = 0.0f, acc1 = 0.0f;
#define CORNER(A,B,C,WXY,WZ) { unsigned idx = ((A)^(B)^(C)) & (TSIZE-1); \
            float2 g = sh[idx]; float w = (WXY)*(WZ); \
            acc0 = fmaf(w, g.x, acc0); acc1 = fmaf(w, g.y, acc1); }
            CORNER(a0, b0, c0, w00, q2)
            CORNER(a0, b0, c1, w00, p2)
            CORNER(a0, b1, c0, w01, q2)
            CORNER(a0, b1, c1, w01, p2)
            CORNER(a1, b0, c0, w10, q2)
            CORNER(a1, b0, c1, w10, p2)
            CORNER(a1, b1, c0, w11, q2)
            CORNER(a1, b1, c1, w11, p2)
#undef CORNER
            res[p][2*l]   = acc0;
            res[p][2*l+1] = acc1;
        }
        __syncthreads();   // protect LDS before next level's staging
    }

    // ---- write out: normal cached stores (L2 merges to full lines) ----
#pragma unroll
    for (int p = 0; p < PPT; ++p) {
        if (nn[p] < npts) {
            floatx4* o = (floatx4*)(out + (size_t)nn[p] * (2*NLVL));
            const floatx4* r = (const floatx4*)res[p];
#pragma unroll
            for (int j = 0; j < 8; ++j)
                o[j] = r[j];
        }
    }
}

extern "C" void kernel_launch(void* const* d_in, const int* in_sizes, int n_in,
                              void* d_out, int out_size, void* d_ws, size_t ws_size,
                              hipStream_t stream) {
    const float*  inp = (const float*)d_in[0];
    const float2* tbl = (const float2*)d_in[1];
    float* out = (float*)d_out;

    // Reproduce NS = [int(16 * b**i)] with host libm (values sit ~1e-14 from
    // exact powers of 2 at i=3,6,9,12,15 — must truncate identically).
    NsArg ns;
    double b = exp((log(512.0) - log(16.0)) / 15.0);
    for (int i = 0; i < NLVL; ++i)
        ns.nf[i] = (float)(int)(16.0 * pow(b, (double)i));

    int npts = in_sizes[0] / 3;
    int blocks = (npts + PPB - 1) / PPB;
    hashgrid_lds<<<dim3(blocks), dim3(BLK), 0, stream>>>(inp, tbl, out, ns, npts);
}